// Round 2
// baseline (534.863 us; speedup 1.0000x reference)
//
#include <hip/hip_runtime.h>

#define NN 50000
#define NE 800000
#define NG 2048
#define F 64

constexpr int SCAN_B = 256;
constexpr int NB = (NN + SCAN_B - 1) / SCAN_B;  // 196 blocks

// ---------------- degree (edge-only in-degree) ----------------
__global__ void deg_kernel(const int* __restrict__ dst, int* __restrict__ deg) {
    int e = blockIdx.x * 256 + threadIdx.x;
    if (e < NE) atomicAdd(&deg[dst[e]], 1);
}

// dinv[v] = rsqrt(deg_edges[v] + 1)   (+1 = self loop)
__global__ void dinv_kernel(const int* __restrict__ deg, float* __restrict__ dinv) {
    int v = blockIdx.x * 256 + threadIdx.x;
    if (v < NN) dinv[v] = rsqrtf((float)(deg[v] + 1));
}

// ---------------- 3-kernel exclusive scan of deg -> rowptr ----------------
__global__ void scan1_kernel(const int* __restrict__ deg, int* __restrict__ bsums) {
    __shared__ int s[256];
    int t = threadIdx.x, i = blockIdx.x * 256 + t;
    s[t] = (i < NN) ? deg[i] : 0;
    __syncthreads();
    for (int off = 128; off > 0; off >>= 1) {
        if (t < off) s[t] += s[t + off];
        __syncthreads();
    }
    if (t == 0) bsums[blockIdx.x] = s[0];
}

__global__ void scan2_kernel(int* __restrict__ bsums, int* __restrict__ rowptr) {
    __shared__ int s[256];
    int t = threadIdx.x;
    int v = (t < NB) ? bsums[t] : 0;
    s[t] = v;
    __syncthreads();
    for (int off = 1; off < 256; off <<= 1) {
        int x = (t >= off) ? s[t - off] : 0;
        __syncthreads();
        s[t] += x;
        __syncthreads();
    }
    if (t < NB) bsums[t] = s[t] - v;   // exclusive block offset
    if (t == 0) rowptr[NN] = NE;
}

__global__ void scan3_kernel(const int* __restrict__ deg, const int* __restrict__ bsums,
                             int* __restrict__ rowptr, int* __restrict__ cursor) {
    __shared__ int s[256];
    int t = threadIdx.x, i = blockIdx.x * 256 + t;
    int v = (i < NN) ? deg[i] : 0;
    s[t] = v;
    __syncthreads();
    for (int off = 1; off < 256; off <<= 1) {
        int x = (t >= off) ? s[t - off] : 0;
        __syncthreads();
        s[t] += x;
        __syncthreads();
    }
    if (i < NN) {
        int rp = bsums[blockIdx.x] + s[t] - v;
        rowptr[i] = rp;
        cursor[i] = rp;
    }
}

// scatter edges into CSR slots (order within a row irrelevant)
__global__ void fill_kernel(const int* __restrict__ src, const int* __restrict__ dst,
                            int* __restrict__ cursor, int* __restrict__ col) {
    int e = blockIdx.x * 256 + threadIdx.x;
    if (e < NE) {
        int slot = atomicAdd(&cursor[dst[e]], 1);
        col[slot] = src[e];
    }
}

// ---------------- g = dinv[v] * (in @ W)   [N,K] @ [K,64] ----------------
template <int K>
__global__ void gemm_kernel(const float* __restrict__ in, const float* __restrict__ W,
                            const float* __restrict__ dinv, float* __restrict__ out) {
    __shared__ float Ws[K * F];
    int t = threadIdx.x;
    for (int i = t; i < K * F; i += 256) Ws[i] = W[i];
    __syncthreads();
    int f = t & 63, ty = t >> 6;
    int n = blockIdx.x * 4 + ty;
    if (n >= NN) return;
    const float* row = in + (long)n * K;
    float acc = 0.f;
#pragma unroll
    for (int k = 0; k < K; ++k) acc = fmaf(row[k], Ws[k * F + f], acc);
    out[(long)n * F + f] = dinv[n] * acc;
}

// ---------------- aggregation: h[v] = relu(dinv[v]*(sum_{u->v} g[u] + g[v]) + b) ----
template <bool POOL>
__global__ void agg_kernel(const float* __restrict__ g, const int* __restrict__ rowptr,
                           const int* __restrict__ col, const float* __restrict__ dinv,
                           const float* __restrict__ bias, float* __restrict__ out,
                           const int* __restrict__ batch, float* __restrict__ pooled,
                           float* __restrict__ counts) {
    int w = threadIdx.x >> 6, lane = threadIdx.x & 63;
    int v = blockIdx.x * 4 + w;
    if (v >= NN) return;
    int beg = rowptr[v], end = rowptr[v + 1];
    float acc = g[(long)v * F + lane];  // self loop
    for (int e = beg; e < end; ++e) {
        int u = col[e];  // wave-uniform broadcast load
        acc += g[(long)u * F + lane];
    }
    float hv = fmaxf(dinv[v] * acc + bias[lane], 0.f);
    if (POOL) {
        int b = batch[v];
        atomicAdd(&pooled[(long)b * F + lane], hv);
        if (lane == 0) atomicAdd(&counts[b], 1.0f);
    } else {
        out[(long)v * F + lane] = hv;
    }
}

// ---------------- head: out = relu(pooled/cnt @ lw1 + lb1) @ lw2 + lb2 ----------------
__global__ void head_kernel(const float* __restrict__ pooled, const float* __restrict__ counts,
                            const float* __restrict__ lw1, const float* __restrict__ lb1,
                            const float* __restrict__ lw2, const float* __restrict__ lb2,
                            float* __restrict__ out) {
    __shared__ float p[F];
    __shared__ float hid[F];
    int gid = blockIdx.x, t = threadIdx.x;
    float cnt = fmaxf(counts[gid], 1.0f);
    p[t] = pooled[(long)gid * F + t] / cnt;
    __syncthreads();
    float acc = lb1[t];
#pragma unroll 8
    for (int k = 0; k < F; ++k) acc = fmaf(p[k], lw1[k * F + t], acc);
    hid[t] = fmaxf(acc, 0.f);
    __syncthreads();
    if (t < 2) {
        float a = lb2[t];
#pragma unroll 8
        for (int k = 0; k < F; ++k) a = fmaf(hid[k], lw2[k * 2 + t], a);
        out[(long)gid * 2 + t] = a;
    }
}

extern "C" void kernel_launch(void* const* d_in, const int* in_sizes, int n_in,
                              void* d_out, int out_size, void* d_ws, size_t ws_size,
                              hipStream_t stream) {
    const float* x    = (const float*)d_in[0];
    const int*   ei   = (const int*)d_in[1];   // [2, NE]: src then dst
    const int*   bat  = (const int*)d_in[2];
    const float* W1   = (const float*)d_in[3];
    const float* b1   = (const float*)d_in[4];
    const float* W2   = (const float*)d_in[5];
    const float* b2   = (const float*)d_in[6];
    const float* W3   = (const float*)d_in[7];
    const float* b3   = (const float*)d_in[8];
    const float* lw1  = (const float*)d_in[9];
    const float* lb1  = (const float*)d_in[10];
    const float* lw2  = (const float*)d_in[11];
    const float* lb2  = (const float*)d_in[12];
    float* out = (float*)d_out;

    const int* src = ei;
    const int* dst = ei + NE;

    // workspace carve-up (256B aligned)
    char* ws = (char*)d_ws;
    size_t off = 0;
    auto carve = [&](size_t bytes) {
        void* p = ws + off;
        off += (bytes + 255) & ~(size_t)255;
        return p;
    };
    int*   deg     = (int*)carve(NN * 4);
    float* dinv    = (float*)carve(NN * 4);
    int*   rowptr  = (int*)carve((NN + 1) * 4);
    int*   cursor  = (int*)carve(NN * 4);
    int*   bsums   = (int*)carve(256 * 4);
    int*   col     = (int*)carve((size_t)NE * 4);
    float* bufA    = (float*)carve((size_t)NN * F * 4);
    float* bufB    = (float*)carve((size_t)NN * F * 4);
    float* pooled  = (float*)carve((size_t)NG * F * 4 + NG * 4);  // pooled + counts contiguous
    float* counts  = pooled + (size_t)NG * F;

    hipMemsetAsync(deg, 0, NN * 4, stream);
    hipMemsetAsync(pooled, 0, ((size_t)NG * F + NG) * 4, stream);

    deg_kernel<<<(NE + 255) / 256, 256, 0, stream>>>(dst, deg);
    dinv_kernel<<<NB, 256, 0, stream>>>(deg, dinv);
    scan1_kernel<<<NB, 256, 0, stream>>>(deg, bsums);
    scan2_kernel<<<1, 256, 0, stream>>>(bsums, rowptr);
    scan3_kernel<<<NB, 256, 0, stream>>>(deg, bsums, rowptr, cursor);
    fill_kernel<<<(NE + 255) / 256, 256, 0, stream>>>(src, dst, cursor, col);

    const int gridN = (NN + 3) / 4;  // 4 nodes (waves) per block
    // layer 1: 32 -> 64
    gemm_kernel<32><<<gridN, 256, 0, stream>>>(x, W1, dinv, bufA);
    agg_kernel<false><<<gridN, 256, 0, stream>>>(bufA, rowptr, col, dinv, b1, bufB,
                                                 nullptr, nullptr, nullptr);
    // layer 2: 64 -> 64
    gemm_kernel<64><<<gridN, 256, 0, stream>>>(bufB, W2, dinv, bufA);
    agg_kernel<false><<<gridN, 256, 0, stream>>>(bufA, rowptr, col, dinv, b2, bufB,
                                                 nullptr, nullptr, nullptr);
    // layer 3: 64 -> 64, fused mean-pool accumulation
    gemm_kernel<64><<<gridN, 256, 0, stream>>>(bufB, W3, dinv, bufA);
    agg_kernel<true><<<gridN, 256, 0, stream>>>(bufA, rowptr, col, dinv, b3, nullptr,
                                                bat, pooled, counts);
    // head MLP
    head_kernel<<<NG, 64, 0, stream>>>(pooled, counts, lw1, lb1, lw2, lb2, out);
}

// Round 3
// 356.560 us; speedup vs baseline: 1.5001x; 1.5001x over previous
//
#include <hip/hip_runtime.h>

#define NN 50000
#define NE 800000
#define NG 2048
#define F 64

constexpr int SCAN_B = 256;
constexpr int NB = (NN + SCAN_B - 1) / SCAN_B;  // 196 blocks

// ---------------- degree (edge-only in-degree) ----------------
__global__ void deg_kernel(const int* __restrict__ dst, int* __restrict__ deg) {
    int e = blockIdx.x * 256 + threadIdx.x;
    if (e < NE) atomicAdd(&deg[dst[e]], 1);
}

// dinv[v] = rsqrt(deg_edges[v] + 1)   (+1 = self loop)
__global__ void dinv_kernel(const int* __restrict__ deg, float* __restrict__ dinv) {
    int v = blockIdx.x * 256 + threadIdx.x;
    if (v < NN) dinv[v] = rsqrtf((float)(deg[v] + 1));
}

// xd[v] = dinv[v] * x[v]   (32 feats as 8 float4 per row)
__global__ void scalex_kernel(const float4* __restrict__ x4, const float* __restrict__ dinv,
                              float4* __restrict__ xd4) {
    int i = blockIdx.x * 256 + threadIdx.x;   // float4 index over NN*8
    if (i < NN * 8) {
        int v = i >> 3;
        float d = dinv[v];
        float4 a = x4[i];
        a.x *= d; a.y *= d; a.z *= d; a.w *= d;
        xd4[i] = a;
    }
}

// ---------------- 3-kernel exclusive scan of deg -> rowptr ----------------
__global__ void scan1_kernel(const int* __restrict__ deg, int* __restrict__ bsums) {
    __shared__ int s[256];
    int t = threadIdx.x, i = blockIdx.x * 256 + t;
    s[t] = (i < NN) ? deg[i] : 0;
    __syncthreads();
    for (int off = 128; off > 0; off >>= 1) {
        if (t < off) s[t] += s[t + off];
        __syncthreads();
    }
    if (t == 0) bsums[blockIdx.x] = s[0];
}

__global__ void scan2_kernel(int* __restrict__ bsums, int* __restrict__ rowptr) {
    __shared__ int s[256];
    int t = threadIdx.x;
    int v = (t < NB) ? bsums[t] : 0;
    s[t] = v;
    __syncthreads();
    for (int off = 1; off < 256; off <<= 1) {
        int x = (t >= off) ? s[t - off] : 0;
        __syncthreads();
        s[t] += x;
        __syncthreads();
    }
    if (t < NB) bsums[t] = s[t] - v;   // exclusive block offset
    if (t == 0) rowptr[NN] = NE;
}

__global__ void scan3_kernel(const int* __restrict__ deg, const int* __restrict__ bsums,
                             int* __restrict__ rowptr, int* __restrict__ cursor) {
    __shared__ int s[256];
    int t = threadIdx.x, i = blockIdx.x * 256 + t;
    int v = (i < NN) ? deg[i] : 0;
    s[t] = v;
    __syncthreads();
    for (int off = 1; off < 256; off <<= 1) {
        int x = (t >= off) ? s[t - off] : 0;
        __syncthreads();
        s[t] += x;
        __syncthreads();
    }
    if (i < NN) {
        int rp = bsums[blockIdx.x] + s[t] - v;
        rowptr[i] = rp;
        cursor[i] = rp;
    }
}

// scatter edges into CSR slots (order within a row irrelevant)
__global__ void fill_kernel(const int* __restrict__ src, const int* __restrict__ dst,
                            int* __restrict__ cursor, int* __restrict__ col) {
    int e = blockIdx.x * 256 + threadIdx.x;
    if (e < NE) {
        int slot = atomicAdd(&cursor[dst[e]], 1);
        col[slot] = src[e];
    }
}

// ---------------- layer-1 aggregation over raw xd (32 feats = 8 float4) ------------
// s[v] = dinv[v] * (sum_{u->v} xd[u] + xd[v])
__global__ void agg32_kernel(const float4* __restrict__ g4, const int* __restrict__ rowptr,
                             const int* __restrict__ col, const float* __restrict__ dinv,
                             float4* __restrict__ out4) {
    int lane = threadIdx.x & 63;
    int v = blockIdx.x * 4 + (threadIdx.x >> 6);
    int slot = lane >> 3, fq = lane & 7;   // 8 slots x 8 float4-lanes
    int beg = rowptr[v], end = rowptr[v + 1];
    float4 acc = {0.f, 0.f, 0.f, 0.f};
    int e = beg + slot;
    for (; e + 8 < end; e += 16) {
        int u0 = col[e], u1 = col[e + 8];
        float4 a = g4[(long)u0 * 8 + fq];
        float4 b = g4[(long)u1 * 8 + fq];
        acc.x += a.x; acc.y += a.y; acc.z += a.z; acc.w += a.w;
        acc.x += b.x; acc.y += b.y; acc.z += b.z; acc.w += b.w;
    }
    if (e < end) {
        int u = col[e];
        float4 a = g4[(long)u * 8 + fq];
        acc.x += a.x; acc.y += a.y; acc.z += a.z; acc.w += a.w;
    }
    // reduce across 8 slots (lane bits 3,4,5)
#pragma unroll
    for (int m = 8; m < 64; m <<= 1) {
        acc.x += __shfl_xor(acc.x, m);
        acc.y += __shfl_xor(acc.y, m);
        acc.z += __shfl_xor(acc.z, m);
        acc.w += __shfl_xor(acc.w, m);
    }
    float4 self = g4[(long)v * 8 + fq];
    float d = dinv[v];
    acc.x = d * (acc.x + self.x);
    acc.y = d * (acc.y + self.y);
    acc.z = d * (acc.z + self.z);
    acc.w = d * (acc.w + self.w);
    if (slot == 0) out4[(long)v * 8 + fq] = acc;
}

// ---------------- aggregation (64 feats = 16 float4), optional pool fuse ----------
// h[v] = relu(dinv[v]*(sum_{u->v} g[u] + g[v]) + b)
template <bool POOL>
__global__ void agg4_kernel(const float4* __restrict__ g4, const int* __restrict__ rowptr,
                            const int* __restrict__ col, const float* __restrict__ dinv,
                            const float4* __restrict__ bias4, float4* __restrict__ out4,
                            const int* __restrict__ batch, float* __restrict__ pooled,
                            float* __restrict__ counts) {
    int lane = threadIdx.x & 63;
    int v = blockIdx.x * 4 + (threadIdx.x >> 6);
    int slot = lane >> 4, fq = lane & 15;  // 4 slots x 16 float4-lanes
    int beg = rowptr[v], end = rowptr[v + 1];
    float4 acc = {0.f, 0.f, 0.f, 0.f};
    int e = beg + slot;
    for (; e + 4 < end; e += 8) {
        int u0 = col[e], u1 = col[e + 4];
        float4 a = g4[(long)u0 * 16 + fq];
        float4 b = g4[(long)u1 * 16 + fq];
        acc.x += a.x; acc.y += a.y; acc.z += a.z; acc.w += a.w;
        acc.x += b.x; acc.y += b.y; acc.z += b.z; acc.w += b.w;
    }
    if (e < end) {
        int u = col[e];
        float4 a = g4[(long)u * 16 + fq];
        acc.x += a.x; acc.y += a.y; acc.z += a.z; acc.w += a.w;
    }
    // reduce across 4 slots (lane bits 4,5)
#pragma unroll
    for (int m = 16; m < 64; m <<= 1) {
        acc.x += __shfl_xor(acc.x, m);
        acc.y += __shfl_xor(acc.y, m);
        acc.z += __shfl_xor(acc.z, m);
        acc.w += __shfl_xor(acc.w, m);
    }
    float4 self = g4[(long)v * 16 + fq];
    float d = dinv[v];
    float4 bb = bias4[fq];
    float4 hv;
    hv.x = fmaxf(fmaf(d, acc.x + self.x, bb.x), 0.f);
    hv.y = fmaxf(fmaf(d, acc.y + self.y, bb.y), 0.f);
    hv.z = fmaxf(fmaf(d, acc.z + self.z, bb.z), 0.f);
    hv.w = fmaxf(fmaf(d, acc.w + self.w, bb.w), 0.f);
    if (slot == 0) {
        if (POOL) {
            int b = batch[v];
            float* p = pooled + (long)b * F + fq * 4;
            atomicAdd(p + 0, hv.x);
            atomicAdd(p + 1, hv.y);
            atomicAdd(p + 2, hv.z);
            atomicAdd(p + 3, hv.w);
            if (lane == 0) atomicAdd(&counts[b], 1.0f);
        } else {
            out4[(long)v * 16 + fq] = hv;
        }
    }
}

// ---------------- GEMM: 16 nodes/block, 256 threads -------------------------------
// RELU_BIAS: out = relu(in@W + b)          (layer-1 path, K=32)
// else:      out = dinv[n] * (in@W)        (pre-aggregation scaling, K=64)
template <int K, bool RELU_BIAS>
__global__ void gemm_kernel(const float* __restrict__ in, const float* __restrict__ W,
                            const float* __restrict__ bias, const float* __restrict__ dinv,
                            float* __restrict__ out) {
    __shared__ float Ws[K * F];
    int t = threadIdx.x;
#pragma unroll
    for (int i = 0; i < K * F / 256; ++i) Ws[i * 256 + t] = W[i * 256 + t];
    __syncthreads();
    int f = t & 63;
    int slot = __builtin_amdgcn_readfirstlane(t >> 6);  // wave-uniform
    int n0 = blockIdx.x * 16 + slot;                    // nodes n0, n0+4, n0+8, n0+12
    float acc0 = 0.f, acc1 = 0.f, acc2 = 0.f, acc3 = 0.f;
    const float* r0 = in + (long)n0 * K;
    const float* r1 = r0 + 4 * K;
    const float* r2 = r0 + 8 * K;
    const float* r3 = r0 + 12 * K;
#pragma unroll
    for (int k = 0; k < K; ++k) {
        float w = Ws[k * F + f];
        acc0 = fmaf(r0[k], w, acc0);
        acc1 = fmaf(r1[k], w, acc1);
        acc2 = fmaf(r2[k], w, acc2);
        acc3 = fmaf(r3[k], w, acc3);
    }
    if (RELU_BIAS) {
        float b = bias[f];
        out[(long)n0 * F + f]        = fmaxf(acc0 + b, 0.f);
        out[(long)(n0 + 4) * F + f]  = fmaxf(acc1 + b, 0.f);
        out[(long)(n0 + 8) * F + f]  = fmaxf(acc2 + b, 0.f);
        out[(long)(n0 + 12) * F + f] = fmaxf(acc3 + b, 0.f);
    } else {
        out[(long)n0 * F + f]        = dinv[n0] * acc0;
        out[(long)(n0 + 4) * F + f]  = dinv[n0 + 4] * acc1;
        out[(long)(n0 + 8) * F + f]  = dinv[n0 + 8] * acc2;
        out[(long)(n0 + 12) * F + f] = dinv[n0 + 12] * acc3;
    }
}

// ---------------- head: out = relu(pooled/cnt @ lw1 + lb1) @ lw2 + lb2 ----------------
__global__ void head_kernel(const float* __restrict__ pooled, const float* __restrict__ counts,
                            const float* __restrict__ lw1, const float* __restrict__ lb1,
                            const float* __restrict__ lw2, const float* __restrict__ lb2,
                            float* __restrict__ out) {
    __shared__ float p[F];
    __shared__ float hid[F];
    int gid = blockIdx.x, t = threadIdx.x;
    float cnt = fmaxf(counts[gid], 1.0f);
    p[t] = pooled[(long)gid * F + t] / cnt;
    __syncthreads();
    float acc = lb1[t];
#pragma unroll 8
    for (int k = 0; k < F; ++k) acc = fmaf(p[k], lw1[k * F + t], acc);
    hid[t] = fmaxf(acc, 0.f);
    __syncthreads();
    if (t < 2) {
        float a = lb2[t];
#pragma unroll 8
        for (int k = 0; k < F; ++k) a = fmaf(hid[k], lw2[k * 2 + t], a);
        out[(long)gid * 2 + t] = a;
    }
}

extern "C" void kernel_launch(void* const* d_in, const int* in_sizes, int n_in,
                              void* d_out, int out_size, void* d_ws, size_t ws_size,
                              hipStream_t stream) {
    const float* x    = (const float*)d_in[0];
    const int*   ei   = (const int*)d_in[1];   // [2, NE]: src then dst
    const int*   bat  = (const int*)d_in[2];
    const float* W1   = (const float*)d_in[3];
    const float* b1   = (const float*)d_in[4];
    const float* W2   = (const float*)d_in[5];
    const float* b2   = (const float*)d_in[6];
    const float* W3   = (const float*)d_in[7];
    const float* b3   = (const float*)d_in[8];
    const float* lw1  = (const float*)d_in[9];
    const float* lb1  = (const float*)d_in[10];
    const float* lw2  = (const float*)d_in[11];
    const float* lb2  = (const float*)d_in[12];
    float* out = (float*)d_out;

    const int* src = ei;
    const int* dst = ei + NE;

    // workspace carve-up (256B aligned)
    char* ws = (char*)d_ws;
    size_t off = 0;
    auto carve = [&](size_t bytes) {
        void* p = ws + off;
        off += (bytes + 255) & ~(size_t)255;
        return p;
    };
    int*   deg     = (int*)carve(NN * 4);
    float* dinv    = (float*)carve(NN * 4);
    int*   rowptr  = (int*)carve((NN + 1) * 4);
    int*   cursor  = (int*)carve(NN * 4);
    int*   bsums   = (int*)carve(256 * 4);
    int*   col     = (int*)carve((size_t)NE * 4);
    float* xd      = (float*)carve((size_t)NN * 32 * 4);
    float* sbuf    = (float*)carve((size_t)NN * 32 * 4);
    float* bufA    = (float*)carve((size_t)NN * F * 4);
    float* bufB    = (float*)carve((size_t)NN * F * 4);
    float* pooled  = (float*)carve((size_t)NG * F * 4 + NG * 4);  // pooled + counts contiguous
    float* counts  = pooled + (size_t)NG * F;

    hipMemsetAsync(deg, 0, NN * 4, stream);
    hipMemsetAsync(pooled, 0, ((size_t)NG * F + NG) * 4, stream);

    deg_kernel<<<(NE + 255) / 256, 256, 0, stream>>>(dst, deg);
    dinv_kernel<<<NB, 256, 0, stream>>>(deg, dinv);
    scalex_kernel<<<(NN * 8 + 255) / 256, 256, 0, stream>>>((const float4*)x, dinv, (float4*)xd);
    scan1_kernel<<<NB, 256, 0, stream>>>(deg, bsums);
    scan2_kernel<<<1, 256, 0, stream>>>(bsums, rowptr);
    scan3_kernel<<<NB, 256, 0, stream>>>(deg, bsums, rowptr, cursor);
    fill_kernel<<<(NE + 255) / 256, 256, 0, stream>>>(src, dst, cursor, col);

    const int gridN = (NN + 3) / 4;    // 12500 blocks, 4 nodes (waves) each
    const int gridG = NN / 16;         // 3125 blocks for gemm

    // layer 1: aggregate raw 32-feat xd, then GEMM with fused bias+relu
    agg32_kernel<<<gridN, 256, 0, stream>>>((const float4*)xd, rowptr, col, dinv, (float4*)sbuf);
    gemm_kernel<32, true><<<gridG, 256, 0, stream>>>(sbuf, W1, b1, dinv, bufA);

    // layer 2: g = dinv*(h1@W2), aggregate with bias+relu
    gemm_kernel<64, false><<<gridG, 256, 0, stream>>>(bufA, W2, nullptr, dinv, bufB);
    agg4_kernel<false><<<gridN, 256, 0, stream>>>((const float4*)bufB, rowptr, col, dinv,
                                                  (const float4*)b2, (float4*)bufA,
                                                  nullptr, nullptr, nullptr);
    // layer 3: fused mean-pool accumulation
    gemm_kernel<64, false><<<gridG, 256, 0, stream>>>(bufA, W3, nullptr, dinv, bufB);
    agg4_kernel<true><<<gridN, 256, 0, stream>>>((const float4*)bufB, rowptr, col, dinv,
                                                 (const float4*)b3, nullptr,
                                                 bat, pooled, counts);
    // head MLP
    head_kernel<<<NG, 64, 0, stream>>>(pooled, counts, lw1, lb1, lw2, lb2, out);
}

// Round 4
// 348.320 us; speedup vs baseline: 1.5356x; 1.0237x over previous
//
#include <hip/hip_runtime.h>

#define NN 50000
#define NE 800000
#define NG 2048
#define F 64

constexpr int SCAN_B = 256;
constexpr int NB = (NN + SCAN_B - 1) / SCAN_B;  // 196 blocks

// ---------------- degree (edge-only in-degree) ----------------
__global__ void deg_kernel(const int* __restrict__ dst, int* __restrict__ deg) {
    int e = blockIdx.x * 256 + threadIdx.x;
    if (e < NE) atomicAdd(&deg[dst[e]], 1);
}

// dinv[v] = rsqrt(deg_edges[v] + 1)   (+1 = self loop)
__global__ void dinv_kernel(const int* __restrict__ deg, float* __restrict__ dinv) {
    int v = blockIdx.x * 256 + threadIdx.x;
    if (v < NN) dinv[v] = rsqrtf((float)(deg[v] + 1));
}

// xd[v] = dinv[v] * x[v]   (32 feats as 8 float4 per row)
__global__ void scalex_kernel(const float4* __restrict__ x4, const float* __restrict__ dinv,
                              float4* __restrict__ xd4) {
    int i = blockIdx.x * 256 + threadIdx.x;   // float4 index over NN*8
    if (i < NN * 8) {
        int v = i >> 3;
        float d = dinv[v];
        float4 a = x4[i];
        a.x *= d; a.y *= d; a.z *= d; a.w *= d;
        xd4[i] = a;
    }
}

// ---------------- 3-kernel exclusive scan of deg -> rowptr ----------------
__global__ void scan1_kernel(const int* __restrict__ deg, int* __restrict__ bsums) {
    __shared__ int s[256];
    int t = threadIdx.x, i = blockIdx.x * 256 + t;
    s[t] = (i < NN) ? deg[i] : 0;
    __syncthreads();
    for (int off = 128; off > 0; off >>= 1) {
        if (t < off) s[t] += s[t + off];
        __syncthreads();
    }
    if (t == 0) bsums[blockIdx.x] = s[0];
}

__global__ void scan2_kernel(int* __restrict__ bsums, int* __restrict__ rowptr) {
    __shared__ int s[256];
    int t = threadIdx.x;
    int v = (t < NB) ? bsums[t] : 0;
    s[t] = v;
    __syncthreads();
    for (int off = 1; off < 256; off <<= 1) {
        int x = (t >= off) ? s[t - off] : 0;
        __syncthreads();
        s[t] += x;
        __syncthreads();
    }
    if (t < NB) bsums[t] = s[t] - v;   // exclusive block offset
    if (t == 0) rowptr[NN] = NE;
}

__global__ void scan3_kernel(const int* __restrict__ deg, const int* __restrict__ bsums,
                             int* __restrict__ rowptr, int* __restrict__ cursor) {
    __shared__ int s[256];
    int t = threadIdx.x, i = blockIdx.x * 256 + t;
    int v = (i < NN) ? deg[i] : 0;
    s[t] = v;
    __syncthreads();
    for (int off = 1; off < 256; off <<= 1) {
        int x = (t >= off) ? s[t - off] : 0;
        __syncthreads();
        s[t] += x;
        __syncthreads();
    }
    if (i < NN) {
        int rp = bsums[blockIdx.x] + s[t] - v;
        rowptr[i] = rp;
        cursor[i] = rp;
    }
}

// scatter edges into CSR slots (order within a row irrelevant)
__global__ void fill_kernel(const int* __restrict__ src, const int* __restrict__ dst,
                            int* __restrict__ cursor, int* __restrict__ col) {
    int e = blockIdx.x * 256 + threadIdx.x;
    if (e < NE) {
        int slot = atomicAdd(&cursor[dst[e]], 1);
        col[slot] = src[e];
    }
}

// ---------------- layer-1 aggregation over raw xd (32 feats = 8 float4) ------------
// s[v] = dinv[v] * (sum_{u->v} xd[u] + xd[v])
// 8 slots x 8 float4-lanes; 32-edge batches (4 per slot), all gathers in flight.
__global__ void agg32_kernel(const float4* __restrict__ g4, const int* __restrict__ rowptr,
                             const int* __restrict__ col, const float* __restrict__ dinv,
                             float4* __restrict__ out4) {
    int lane = threadIdx.x & 63;
    int v = blockIdx.x * 4 + (threadIdx.x >> 6);
    int slot = lane >> 3, fq = lane & 7;
    int beg = rowptr[v], end = rowptr[v + 1];
    float4 acc = {0.f, 0.f, 0.f, 0.f};
    for (int base = beg; base < end; base += 32) {
        float4 a[4];
        float w[4];
#pragma unroll
        for (int j = 0; j < 4; ++j) {
            int e = base + slot + j * 8;
            int ce = (e < end) ? e : (end - 1);   // clamp: always a valid edge slot
            w[j] = (e < end) ? 1.f : 0.f;
            int u = col[ce];
            a[j] = g4[(long)u * 8 + fq];
        }
#pragma unroll
        for (int j = 0; j < 4; ++j) {
            acc.x = fmaf(w[j], a[j].x, acc.x);
            acc.y = fmaf(w[j], a[j].y, acc.y);
            acc.z = fmaf(w[j], a[j].z, acc.z);
            acc.w = fmaf(w[j], a[j].w, acc.w);
        }
    }
    // reduce across 8 slots (lane bits 3,4,5)
#pragma unroll
    for (int m = 8; m < 64; m <<= 1) {
        acc.x += __shfl_xor(acc.x, m);
        acc.y += __shfl_xor(acc.y, m);
        acc.z += __shfl_xor(acc.z, m);
        acc.w += __shfl_xor(acc.w, m);
    }
    float4 self = g4[(long)v * 8 + fq];
    float d = dinv[v];
    acc.x = d * (acc.x + self.x);
    acc.y = d * (acc.y + self.y);
    acc.z = d * (acc.z + self.z);
    acc.w = d * (acc.w + self.w);
    if (slot == 0) out4[(long)v * 8 + fq] = acc;
}

// ---------------- aggregation (64 feats = 16 float4), optional pool fuse ----------
// h[v] = relu(dinv[v]*(sum_{u->v} g[u] + g[v]) + b)
// 4 slots x 16 float4-lanes; 32-edge batches (8 per slot), all gathers in flight.
template <bool POOL>
__global__ void agg4_kernel(const float4* __restrict__ g4, const int* __restrict__ rowptr,
                            const int* __restrict__ col, const float* __restrict__ dinv,
                            const float4* __restrict__ bias4, float4* __restrict__ out4,
                            const int* __restrict__ batch, float* __restrict__ pooled,
                            float* __restrict__ counts) {
    int lane = threadIdx.x & 63;
    int v = blockIdx.x * 4 + (threadIdx.x >> 6);
    int slot = lane >> 4, fq = lane & 15;
    int beg = rowptr[v], end = rowptr[v + 1];
    float4 acc = {0.f, 0.f, 0.f, 0.f};
    for (int base = beg; base < end; base += 32) {
        float4 a[8];
        float w[8];
#pragma unroll
        for (int j = 0; j < 8; ++j) {
            int e = base + slot + j * 4;
            int ce = (e < end) ? e : (end - 1);   // clamp: always a valid edge slot
            w[j] = (e < end) ? 1.f : 0.f;
            int u = col[ce];
            a[j] = g4[(long)u * 16 + fq];
        }
#pragma unroll
        for (int j = 0; j < 8; ++j) {
            acc.x = fmaf(w[j], a[j].x, acc.x);
            acc.y = fmaf(w[j], a[j].y, acc.y);
            acc.z = fmaf(w[j], a[j].z, acc.z);
            acc.w = fmaf(w[j], a[j].w, acc.w);
        }
    }
    // reduce across 4 slots (lane bits 4,5)
#pragma unroll
    for (int m = 16; m < 64; m <<= 1) {
        acc.x += __shfl_xor(acc.x, m);
        acc.y += __shfl_xor(acc.y, m);
        acc.z += __shfl_xor(acc.z, m);
        acc.w += __shfl_xor(acc.w, m);
    }
    float4 self = g4[(long)v * 16 + fq];
    float d = dinv[v];
    float4 bb = bias4[fq];
    float4 hv;
    hv.x = fmaxf(fmaf(d, acc.x + self.x, bb.x), 0.f);
    hv.y = fmaxf(fmaf(d, acc.y + self.y, bb.y), 0.f);
    hv.z = fmaxf(fmaf(d, acc.z + self.z, bb.z), 0.f);
    hv.w = fmaxf(fmaf(d, acc.w + self.w, bb.w), 0.f);
    if (slot == 0) {
        if (POOL) {
            int b = batch[v];
            float* p = pooled + (long)b * F + fq * 4;
            atomicAdd(p + 0, hv.x);
            atomicAdd(p + 1, hv.y);
            atomicAdd(p + 2, hv.z);
            atomicAdd(p + 3, hv.w);
            if (lane == 0) atomicAdd(&counts[b], 1.0f);
        } else {
            out4[(long)v * 16 + fq] = hv;
        }
    }
}

// ---------------- GEMM: 16 nodes/block, 256 threads -------------------------------
// RELU_BIAS: out = relu(in@W + b)          (layer-1 path, K=32)
// else:      out = dinv[n] * (in@W)        (pre-aggregation scaling, K=64)
template <int K, bool RELU_BIAS>
__global__ void gemm_kernel(const float* __restrict__ in, const float* __restrict__ W,
                            const float* __restrict__ bias, const float* __restrict__ dinv,
                            float* __restrict__ out) {
    __shared__ float Ws[K * F];
    int t = threadIdx.x;
#pragma unroll
    for (int i = 0; i < K * F / 256; ++i) Ws[i * 256 + t] = W[i * 256 + t];
    __syncthreads();
    int f = t & 63;
    int slot = __builtin_amdgcn_readfirstlane(t >> 6);  // wave-uniform
    int n0 = blockIdx.x * 16 + slot;                    // nodes n0, n0+4, n0+8, n0+12
    float acc0 = 0.f, acc1 = 0.f, acc2 = 0.f, acc3 = 0.f;
    const float* r0 = in + (long)n0 * K;
    const float* r1 = r0 + 4 * K;
    const float* r2 = r0 + 8 * K;
    const float* r3 = r0 + 12 * K;
#pragma unroll
    for (int k = 0; k < K; ++k) {
        float w = Ws[k * F + f];
        acc0 = fmaf(r0[k], w, acc0);
        acc1 = fmaf(r1[k], w, acc1);
        acc2 = fmaf(r2[k], w, acc2);
        acc3 = fmaf(r3[k], w, acc3);
    }
    if (RELU_BIAS) {
        float b = bias[f];
        out[(long)n0 * F + f]        = fmaxf(acc0 + b, 0.f);
        out[(long)(n0 + 4) * F + f]  = fmaxf(acc1 + b, 0.f);
        out[(long)(n0 + 8) * F + f]  = fmaxf(acc2 + b, 0.f);
        out[(long)(n0 + 12) * F + f] = fmaxf(acc3 + b, 0.f);
    } else {
        out[(long)n0 * F + f]        = dinv[n0] * acc0;
        out[(long)(n0 + 4) * F + f]  = dinv[n0 + 4] * acc1;
        out[(long)(n0 + 8) * F + f]  = dinv[n0 + 8] * acc2;
        out[(long)(n0 + 12) * F + f] = dinv[n0 + 12] * acc3;
    }
}

// ---------------- head: out = relu(pooled/cnt @ lw1 + lb1) @ lw2 + lb2 ----------------
__global__ void head_kernel(const float* __restrict__ pooled, const float* __restrict__ counts,
                            const float* __restrict__ lw1, const float* __restrict__ lb1,
                            const float* __restrict__ lw2, const float* __restrict__ lb2,
                            float* __restrict__ out) {
    __shared__ float p[F];
    __shared__ float hid[F];
    int gid = blockIdx.x, t = threadIdx.x;
    float cnt = fmaxf(counts[gid], 1.0f);
    p[t] = pooled[(long)gid * F + t] / cnt;
    __syncthreads();
    float acc = lb1[t];
#pragma unroll 8
    for (int k = 0; k < F; ++k) acc = fmaf(p[k], lw1[k * F + t], acc);
    hid[t] = fmaxf(acc, 0.f);
    __syncthreads();
    if (t < 2) {
        float a = lb2[t];
#pragma unroll 8
        for (int k = 0; k < F; ++k) a = fmaf(hid[k], lw2[k * 2 + t], a);
        out[(long)gid * 2 + t] = a;
    }
}

extern "C" void kernel_launch(void* const* d_in, const int* in_sizes, int n_in,
                              void* d_out, int out_size, void* d_ws, size_t ws_size,
                              hipStream_t stream) {
    const float* x    = (const float*)d_in[0];
    const int*   ei   = (const int*)d_in[1];   // [2, NE]: src then dst
    const int*   bat  = (const int*)d_in[2];
    const float* W1   = (const float*)d_in[3];
    const float* b1   = (const float*)d_in[4];
    const float* W2   = (const float*)d_in[5];
    const float* b2   = (const float*)d_in[6];
    const float* W3   = (const float*)d_in[7];
    const float* b3   = (const float*)d_in[8];
    const float* lw1  = (const float*)d_in[9];
    const float* lb1  = (const float*)d_in[10];
    const float* lw2  = (const float*)d_in[11];
    const float* lb2  = (const float*)d_in[12];
    float* out = (float*)d_out;

    const int* src = ei;
    const int* dst = ei + NE;

    // workspace carve-up (256B aligned)
    char* ws = (char*)d_ws;
    size_t off = 0;
    auto carve = [&](size_t bytes) {
        void* p = ws + off;
        off += (bytes + 255) & ~(size_t)255;
        return p;
    };
    int*   deg     = (int*)carve(NN * 4);
    float* dinv    = (float*)carve(NN * 4);
    int*   rowptr  = (int*)carve((NN + 1) * 4);
    int*   cursor  = (int*)carve(NN * 4);
    int*   bsums   = (int*)carve(256 * 4);
    int*   col     = (int*)carve((size_t)NE * 4);
    float* xd      = (float*)carve((size_t)NN * 32 * 4);
    float* sbuf    = (float*)carve((size_t)NN * 32 * 4);
    float* bufA    = (float*)carve((size_t)NN * F * 4);
    float* bufB    = (float*)carve((size_t)NN * F * 4);
    float* pooled  = (float*)carve((size_t)NG * F * 4 + NG * 4);  // pooled + counts contiguous
    float* counts  = pooled + (size_t)NG * F;

    hipMemsetAsync(deg, 0, NN * 4, stream);
    hipMemsetAsync(pooled, 0, ((size_t)NG * F + NG) * 4, stream);

    deg_kernel<<<(NE + 255) / 256, 256, 0, stream>>>(dst, deg);
    dinv_kernel<<<NB, 256, 0, stream>>>(deg, dinv);
    scalex_kernel<<<(NN * 8 + 255) / 256, 256, 0, stream>>>((const float4*)x, dinv, (float4*)xd);
    scan1_kernel<<<NB, 256, 0, stream>>>(deg, bsums);
    scan2_kernel<<<1, 256, 0, stream>>>(bsums, rowptr);
    scan3_kernel<<<NB, 256, 0, stream>>>(deg, bsums, rowptr, cursor);
    fill_kernel<<<(NE + 255) / 256, 256, 0, stream>>>(src, dst, cursor, col);

    const int gridN = (NN + 3) / 4;    // 12500 blocks, 4 nodes (waves) each
    const int gridG = NN / 16;         // 3125 blocks for gemm

    // layer 1: aggregate raw 32-feat xd, then GEMM with fused bias+relu
    agg32_kernel<<<gridN, 256, 0, stream>>>((const float4*)xd, rowptr, col, dinv, (float4*)sbuf);
    gemm_kernel<32, true><<<gridG, 256, 0, stream>>>(sbuf, W1, b1, dinv, bufA);

    // layer 2: g = dinv*(h1@W2), aggregate with bias+relu
    gemm_kernel<64, false><<<gridG, 256, 0, stream>>>(bufA, W2, nullptr, dinv, bufB);
    agg4_kernel<false><<<gridN, 256, 0, stream>>>((const float4*)bufB, rowptr, col, dinv,
                                                  (const float4*)b2, (float4*)bufA,
                                                  nullptr, nullptr, nullptr);
    // layer 3: fused mean-pool accumulation
    gemm_kernel<64, false><<<gridG, 256, 0, stream>>>(bufA, W3, nullptr, dinv, bufB);
    agg4_kernel<true><<<gridN, 256, 0, stream>>>((const float4*)bufB, rowptr, col, dinv,
                                                 (const float4*)b3, nullptr,
                                                 bat, pooled, counts);
    // head MLP
    head_kernel<<<NG, 64, 0, stream>>>(pooled, counts, lw1, lb1, lw2, lb2, out);
}